// Round 4
// baseline (523.824 us; speedup 1.0000x reference)
//
#include <hip/hip_runtime.h>

typedef __bf16   bf16x8 __attribute__((ext_vector_type(8)));
typedef float    f32x4  __attribute__((ext_vector_type(4)));
typedef float    f32x2  __attribute__((ext_vector_type(2)));
typedef uint32_t u32x4  __attribute__((ext_vector_type(4)));

constexpr int N_ = 16384;
constexpr int D_ = 16;
constexpr int P_ = 8;
constexpr int H_ = 128;
constexpr int M_ = 50;

// pack two f32 -> one bf16x2 register word (round-half-up; 3 VALU ops)
__device__ __forceinline__ uint32_t pk_bf16(float a, float b) {
    uint32_t ua = __builtin_bit_cast(uint32_t, a) + 0x8000u;
    uint32_t ub = __builtin_bit_cast(uint32_t, b) + 0x8000u;
    return __builtin_amdgcn_perm(ub, ua, 0x07060302u);   // [a.hi16 | b.hi16]
}
__device__ __forceinline__ uint32_t pk_relu_bf16(float a, float b) {
    return pk_bf16(fmaxf(a, 0.0f), fmaxf(b, 0.0f));
}

// R4: two cooperating waves per 16-particle tile (H-split) for 2 waves/SIMD
// MFMA<->VALU overlap (m114). Wave w owns hidden features 64w..64w+63:
//   layer1: 4 ct-chains; layer2: 4 ct-chains x 4 kt; layer3: partial Z over
//   own kt pair. Exchange 1: packed h1 B-fragments via LDS (contiguous
//   16B/lane b128, conflict-free). Exchange 2: partial Z in f32. Math is
//   bit-identical to the R3 single-wave kernel.
__global__ __launch_bounds__(128, 2)
void sde_fused(const float* __restrict__ X0,
               const float* __restrict__ V0,
               const float* __restrict__ Yobs,
               const float* __restrict__ noise,
               const float* __restrict__ W1, const float* __restrict__ b1,
               const float* __restrict__ W2, const float* __restrict__ b2,
               const float* __restrict__ W3, const float* __restrict__ b3,
               float* __restrict__ out)
{
    __shared__ u32x4 ex1[4][64];   // h1 B-fragments, slot = global kt
    __shared__ f32x4 ex2[2][64];   // partial Z, slot = wave

    const int tid  = threadIdx.x;
    const int wv   = tid >> 6;      // wave 0/1
    const int lane = tid & 63;
    const int n    = lane & 15;     // particle within tile
    const int q    = lane >> 4;     // quad
    const int gr   = blockIdx.x * 16 + n;

    const float dt   = 0.02f;
    const float sqdt = 0.1414213562373095f;

    // ---- weight fragments for this wave's ct = wv*4+c ----
    bf16x8 w1f[4];
#pragma unroll
    for (int c = 0; c < 4; ++c) {
        int ct = wv * 4 + c;
        u32x4 u;
        u[0] = pk_bf16(W1[(1 + q * 4 + 0) * H_ + ct * 16 + n],
                       W1[(1 + q * 4 + 1) * H_ + ct * 16 + n]);
        u[1] = pk_bf16(W1[(1 + q * 4 + 2) * H_ + ct * 16 + n],
                       W1[(1 + q * 4 + 3) * H_ + ct * 16 + n]);
        u[2] = pk_bf16(W1[(17 + q * 2 + 0) * H_ + ct * 16 + n],
                       W1[(17 + q * 2 + 1) * H_ + ct * 16 + n]);
        u[3] = (q == 0) ? pk_bf16(b1[ct * 16 + n], W1[ct * 16 + n]) : 0u;
        w1f[c] = __builtin_bit_cast(bf16x8, u);
    }
    bf16x8 w2f[4][4];
#pragma unroll
    for (int c = 0; c < 4; ++c) {
        int ct = wv * 4 + c;
#pragma unroll
        for (int kt = 0; kt < 4; ++kt) {
            u32x4 u;
#pragma unroll
            for (int w = 0; w < 4; ++w) {
                int h0 = (kt * 2 + (w >> 1)) * 16 + q * 4 + (w & 1) * 2;
                u[w] = pk_bf16(W2[h0 * H_ + ct * 16 + n],
                               W2[(h0 + 1) * H_ + ct * 16 + n]);
            }
            w2f[c][kt] = __builtin_bit_cast(bf16x8, u);
        }
    }
    bf16x8 w3f[2];   // own kt = wv*2 + i
#pragma unroll
    for (int i = 0; i < 2; ++i) {
        int kt = wv * 2 + i;
        u32x4 u;
#pragma unroll
        for (int w = 0; w < 4; ++w) {
            int h0 = (kt * 2 + (w >> 1)) * 16 + q * 4 + (w & 1) * 2;
            u[w] = pk_bf16(W3[h0 * D_ + n], W3[(h0 + 1) * D_ + n]);
        }
        w3f[i] = __builtin_bit_cast(bf16x8, u);
    }
    f32x4 b2r[4];
#pragma unroll
    for (int c = 0; c < 4; ++c)
#pragma unroll
        for (int r = 0; r < 4; ++r) b2r[c][r] = b2[(wv * 4 + c) * 16 + q * 4 + r];
    f32x4 zinit;   // b3 added once (by wave 0's partial)
#pragma unroll
    for (int r = 0; r < 4; ++r) zinit[r] = (wv == 0) ? b3[q * 4 + r] : 0.0f;

    // ---- state (duplicated in both waves; identical values) ----
    f32x4 x = *(const f32x4*)&X0[gr * D_ + q * 4];
    f32x2 y2 = *(const f32x2*)&Yobs[gr * P_ + q * 2];
    const uint32_t yw = pk_bf16(y2[0], y2[1]);

    const float* npb = noise + (size_t)gr * D_ + q * 4;
    f32x4 e0 = *(const f32x4*)npb;
    f32x4 e1 = *(const f32x4*)(npb + (size_t)N_ * D_);
    float t = 0.0f;
    float vacc = 0.0f;

    for (int m = 0; m < M_; ++m) {
        int mp = (m + 2 < M_) ? (m + 2) : (M_ - 1);
        f32x4 e2 = *(const f32x4*)(npb + (size_t)mp * N_ * D_);

        // ---- layer 1 B fragment: [X(4) | Y(2) | one | t] (same both waves) ----
        u32x4 au;
        au[0] = pk_bf16(x[0], x[1]);
        au[1] = pk_bf16(x[2], x[3]);
        au[2] = yw;
        au[3] = (q == 0) ? pk_bf16(1.0f, t) : 0u;
        bf16x8 a0 = __builtin_bit_cast(bf16x8, au);

        // ---- layer 1: own 4 ct-chains ----
        f32x4 h1c[4];
#pragma unroll
        for (int c = 0; c < 4; ++c)
            h1c[c] = __builtin_amdgcn_mfma_f32_16x16x32_bf16(
                w1f[c], a0, (f32x4){0.f, 0.f, 0.f, 0.f}, 0, 0, 0);

        // pack own 2 B-fragments (global kt = 2wv, 2wv+1)
        u32x4 p0, p1;
        p0[0] = pk_relu_bf16(h1c[0][0], h1c[0][1]);
        p0[1] = pk_relu_bf16(h1c[0][2], h1c[0][3]);
        p0[2] = pk_relu_bf16(h1c[1][0], h1c[1][1]);
        p0[3] = pk_relu_bf16(h1c[1][2], h1c[1][3]);
        p1[0] = pk_relu_bf16(h1c[2][0], h1c[2][1]);
        p1[1] = pk_relu_bf16(h1c[2][2], h1c[2][3]);
        p1[2] = pk_relu_bf16(h1c[3][0], h1c[3][1]);
        p1[3] = pk_relu_bf16(h1c[3][2], h1c[3][3]);

        ex1[2 * wv + 0][lane] = p0;
        ex1[2 * wv + 1][lane] = p1;
        __syncthreads();

        bf16x8 h1b[4];
        h1b[2 * wv + 0] = __builtin_bit_cast(bf16x8, p0);
        h1b[2 * wv + 1] = __builtin_bit_cast(bf16x8, p1);
        {
            int o = 2 - 2 * wv;
            h1b[o + 0] = __builtin_bit_cast(bf16x8, ex1[o + 0][lane]);
            h1b[o + 1] = __builtin_bit_cast(bf16x8, ex1[o + 1][lane]);
        }

        // ---- layer 2: own 4 ct-chains over full K ----
        f32x4 h2c[4];
#pragma unroll
        for (int c = 0; c < 4; ++c) {
            f32x4 cc = b2r[c];
#pragma unroll
            for (int kt = 0; kt < 4; ++kt)
                cc = __builtin_amdgcn_mfma_f32_16x16x32_bf16(w2f[c][kt], h1b[kt], cc, 0, 0, 0);
            h2c[c] = cc;
        }

        // pack own h2 B-fragments (exactly global kt = 2wv, 2wv+1)
        u32x4 q0, q1;
        q0[0] = pk_relu_bf16(h2c[0][0], h2c[0][1]);
        q0[1] = pk_relu_bf16(h2c[0][2], h2c[0][3]);
        q0[2] = pk_relu_bf16(h2c[1][0], h2c[1][1]);
        q0[3] = pk_relu_bf16(h2c[1][2], h2c[1][3]);
        q1[0] = pk_relu_bf16(h2c[2][0], h2c[2][1]);
        q1[1] = pk_relu_bf16(h2c[2][2], h2c[2][3]);
        q1[2] = pk_relu_bf16(h2c[3][0], h2c[3][1]);
        q1[3] = pk_relu_bf16(h2c[3][2], h2c[3][3]);

        // ---- layer 3: partial Z over own kt pair ----
        f32x4 zp = __builtin_amdgcn_mfma_f32_16x16x32_bf16(
            w3f[0], __builtin_bit_cast(bf16x8, q0), zinit, 0, 0, 0);
        zp = __builtin_amdgcn_mfma_f32_16x16x32_bf16(
            w3f[1], __builtin_bit_cast(bf16x8, q1), zp, 0, 0, 0);

        ex2[wv][lane] = zp;
        __syncthreads();
        f32x4 zo = ex2[1 - wv][lane];

        // ---- V partial + X update (identical in both waves) ----
#pragma unroll
        for (int r = 0; r < 4; ++r) {
            float z  = zp[r] + zo[r];
            float wn = sqdt * e0[r];
            vacc = fmaf(z, wn, fmaf(0.01f * z, z, vacc));   // z*wn + dt/2*z^2
            x[r] = fmaf(x[r], 0.98f, wn);                   // (1-dt)*x + wn
        }

        e0 = e1; e1 = e2;
        t += dt;
    }

    // ---- final V reduction across the 4 q-groups (within this wave) ----
    float part = vacc;
    part += __shfl_xor(part, 16);
    part += __shfl_xor(part, 32);
    float v = V0[gr] + part;

    if (wv == 0) {
        *(f32x4*)&out[gr * D_ + q * 4] = x;
        if (q == 0) out[N_ * D_ + gr] = v;
    }
}

extern "C" void kernel_launch(void* const* d_in, const int* in_sizes, int n_in,
                              void* d_out, int out_size, void* d_ws, size_t ws_size,
                              hipStream_t stream)
{
    const float* X0 = (const float*)d_in[0];
    const float* V0 = (const float*)d_in[1];
    const float* Y  = (const float*)d_in[2];
    const float* nz = (const float*)d_in[3];
    const float* W1 = (const float*)d_in[4];
    const float* b1 = (const float*)d_in[5];
    const float* W2 = (const float*)d_in[6];
    const float* b2 = (const float*)d_in[7];
    const float* W3 = (const float*)d_in[8];
    const float* b3 = (const float*)d_in[9];
    float* out = (float*)d_out;

    sde_fused<<<N_ / 16, 128, 0, stream>>>(X0, V0, Y, nz, W1, b1, W2, b2, W3, b3, out);
}

// Round 5
// 146.344 us; speedup vs baseline: 3.5794x; 3.5794x over previous
//
#include <hip/hip_runtime.h>

typedef __bf16   bf16x8 __attribute__((ext_vector_type(8)));
typedef float    f32x4  __attribute__((ext_vector_type(4)));
typedef float    f32x2  __attribute__((ext_vector_type(2)));
typedef uint32_t u32x4  __attribute__((ext_vector_type(4)));

constexpr int N_ = 16384;
constexpr int D_ = 16;
constexpr int P_ = 8;
constexpr int H_ = 128;
constexpr int M_ = 50;

// pack two f32 -> one bf16x2 register word (round-half-up; 3 VALU ops)
__device__ __forceinline__ uint32_t pk_bf16(float a, float b) {
    uint32_t ua = __builtin_bit_cast(uint32_t, a) + 0x8000u;
    uint32_t ub = __builtin_bit_cast(uint32_t, b) + 0x8000u;
    return __builtin_amdgcn_perm(ub, ua, 0x07060302u);   // [a.hi16 | b.hi16]
}
__device__ __forceinline__ uint32_t pk_relu_bf16(float a, float b) {
    return pk_bf16(fmaxf(a, 0.0f), fmaxf(b, 0.0f));
}

// R5 = R4 (2 cooperating waves per 16-particle tile, H-split, 2 waves/SIMD
// MFMA<->VALU overlap) with the scratch pathology removed: NO register array
// is indexed by a runtime value. Exchanged fragments round-trip through LDS;
// reads use static slot indices (each wave re-reads its own slots too).
__global__ __launch_bounds__(128, 2)
void sde_fused(const float* __restrict__ X0,
               const float* __restrict__ V0,
               const float* __restrict__ Yobs,
               const float* __restrict__ noise,
               const float* __restrict__ W1, const float* __restrict__ b1,
               const float* __restrict__ W2, const float* __restrict__ b2,
               const float* __restrict__ W3, const float* __restrict__ b3,
               float* __restrict__ out)
{
    __shared__ u32x4 ex1[4][64];   // h1 B-fragments, slot = global kt
    __shared__ f32x4 ex2[2][64];   // partial Z, slot = wave

    const int tid  = threadIdx.x;
    const int wv   = tid >> 6;      // wave 0/1
    const int lane = tid & 63;
    const int n    = lane & 15;     // particle within tile
    const int q    = lane >> 4;     // quad
    const int gr   = blockIdx.x * 16 + n;

    const float dt   = 0.02f;
    const float sqdt = 0.1414213562373095f;

    // ---- weight fragments for this wave's ct = wv*4+c (static array idx c) ----
    bf16x8 w1f[4];
#pragma unroll
    for (int c = 0; c < 4; ++c) {
        int ct = wv * 4 + c;
        u32x4 u;
        u[0] = pk_bf16(W1[(1 + q * 4 + 0) * H_ + ct * 16 + n],
                       W1[(1 + q * 4 + 1) * H_ + ct * 16 + n]);
        u[1] = pk_bf16(W1[(1 + q * 4 + 2) * H_ + ct * 16 + n],
                       W1[(1 + q * 4 + 3) * H_ + ct * 16 + n]);
        u[2] = pk_bf16(W1[(17 + q * 2 + 0) * H_ + ct * 16 + n],
                       W1[(17 + q * 2 + 1) * H_ + ct * 16 + n]);
        u[3] = (q == 0) ? pk_bf16(b1[ct * 16 + n], W1[ct * 16 + n]) : 0u;
        w1f[c] = __builtin_bit_cast(bf16x8, u);
    }
    bf16x8 w2f[4][4];
#pragma unroll
    for (int c = 0; c < 4; ++c) {
        int ct = wv * 4 + c;
#pragma unroll
        for (int kt = 0; kt < 4; ++kt) {
            u32x4 u;
#pragma unroll
            for (int w = 0; w < 4; ++w) {
                int h0 = (kt * 2 + (w >> 1)) * 16 + q * 4 + (w & 1) * 2;
                u[w] = pk_bf16(W2[h0 * H_ + ct * 16 + n],
                               W2[(h0 + 1) * H_ + ct * 16 + n]);
            }
            w2f[c][kt] = __builtin_bit_cast(bf16x8, u);
        }
    }
    bf16x8 w3f[2];   // own kt = wv*2 + i (array idx i static)
#pragma unroll
    for (int i = 0; i < 2; ++i) {
        int kt = wv * 2 + i;
        u32x4 u;
#pragma unroll
        for (int w = 0; w < 4; ++w) {
            int h0 = (kt * 2 + (w >> 1)) * 16 + q * 4 + (w & 1) * 2;
            u[w] = pk_bf16(W3[h0 * D_ + n], W3[(h0 + 1) * D_ + n]);
        }
        w3f[i] = __builtin_bit_cast(bf16x8, u);
    }
    f32x4 b2r[4];
#pragma unroll
    for (int c = 0; c < 4; ++c)
#pragma unroll
        for (int r = 0; r < 4; ++r) b2r[c][r] = b2[(wv * 4 + c) * 16 + q * 4 + r];
    f32x4 zinit;   // b3 folded into wave 0's partial only
#pragma unroll
    for (int r = 0; r < 4; ++r) zinit[r] = (wv == 0) ? b3[q * 4 + r] : 0.0f;

    // ---- state (duplicated in both waves; identical values) ----
    f32x4 x = *(const f32x4*)&X0[gr * D_ + q * 4];
    f32x2 y2 = *(const f32x2*)&Yobs[gr * P_ + q * 2];
    const uint32_t yw = pk_bf16(y2[0], y2[1]);

    const float* npb = noise + (size_t)gr * D_ + q * 4;
    f32x4 e0 = *(const f32x4*)npb;
    f32x4 e1 = *(const f32x4*)(npb + (size_t)N_ * D_);
    float t = 0.0f;
    float vacc = 0.0f;

    // LDS write pointers for this wave (dynamic LDS ADDRESS is fine)
    u32x4* ex1w0 = &ex1[2 * wv + 0][lane];
    u32x4* ex1w1 = &ex1[2 * wv + 1][lane];
    f32x4* ex2w  = &ex2[wv][lane];

    for (int m = 0; m < M_; ++m) {
        int mp = (m + 2 < M_) ? (m + 2) : (M_ - 1);
        f32x4 e2 = *(const f32x4*)(npb + (size_t)mp * N_ * D_);

        // ---- layer 1 B fragment: [X(4) | Y(2) | one | t] (same both waves) ----
        u32x4 au;
        au[0] = pk_bf16(x[0], x[1]);
        au[1] = pk_bf16(x[2], x[3]);
        au[2] = yw;
        au[3] = (q == 0) ? pk_bf16(1.0f, t) : 0u;
        bf16x8 a0 = __builtin_bit_cast(bf16x8, au);

        // ---- layer 1: own 4 ct-chains ----
        f32x4 h1c[4];
#pragma unroll
        for (int c = 0; c < 4; ++c)
            h1c[c] = __builtin_amdgcn_mfma_f32_16x16x32_bf16(
                w1f[c], a0, (f32x4){0.f, 0.f, 0.f, 0.f}, 0, 0, 0);

        // pack own 2 B-fragments (these land in global kt slots 2wv, 2wv+1)
        u32x4 p0, p1;
        p0[0] = pk_relu_bf16(h1c[0][0], h1c[0][1]);
        p0[1] = pk_relu_bf16(h1c[0][2], h1c[0][3]);
        p0[2] = pk_relu_bf16(h1c[1][0], h1c[1][1]);
        p0[3] = pk_relu_bf16(h1c[1][2], h1c[1][3]);
        p1[0] = pk_relu_bf16(h1c[2][0], h1c[2][1]);
        p1[1] = pk_relu_bf16(h1c[2][2], h1c[2][3]);
        p1[2] = pk_relu_bf16(h1c[3][0], h1c[3][1]);
        p1[3] = pk_relu_bf16(h1c[3][2], h1c[3][3]);

        *ex1w0 = p0;
        *ex1w1 = p1;
        __syncthreads();

        // read ALL 4 kt slots with static indices (own two included)
        bf16x8 h1b0 = __builtin_bit_cast(bf16x8, ex1[0][lane]);
        bf16x8 h1b1 = __builtin_bit_cast(bf16x8, ex1[1][lane]);
        bf16x8 h1b2 = __builtin_bit_cast(bf16x8, ex1[2][lane]);
        bf16x8 h1b3 = __builtin_bit_cast(bf16x8, ex1[3][lane]);

        // ---- layer 2: own 4 ct-chains over full K ----
        f32x4 h2c[4];
#pragma unroll
        for (int c = 0; c < 4; ++c) {
            f32x4 cc = b2r[c];
            cc = __builtin_amdgcn_mfma_f32_16x16x32_bf16(w2f[c][0], h1b0, cc, 0, 0, 0);
            cc = __builtin_amdgcn_mfma_f32_16x16x32_bf16(w2f[c][1], h1b1, cc, 0, 0, 0);
            cc = __builtin_amdgcn_mfma_f32_16x16x32_bf16(w2f[c][2], h1b2, cc, 0, 0, 0);
            cc = __builtin_amdgcn_mfma_f32_16x16x32_bf16(w2f[c][3], h1b3, cc, 0, 0, 0);
            h2c[c] = cc;
        }

        // pack own h2 B-fragments (exactly the two kt this wave's w3f covers)
        u32x4 q0, q1;
        q0[0] = pk_relu_bf16(h2c[0][0], h2c[0][1]);
        q0[1] = pk_relu_bf16(h2c[0][2], h2c[0][3]);
        q0[2] = pk_relu_bf16(h2c[1][0], h2c[1][1]);
        q0[3] = pk_relu_bf16(h2c[1][2], h2c[1][3]);
        q1[0] = pk_relu_bf16(h2c[2][0], h2c[2][1]);
        q1[1] = pk_relu_bf16(h2c[2][2], h2c[2][3]);
        q1[2] = pk_relu_bf16(h2c[3][0], h2c[3][1]);
        q1[3] = pk_relu_bf16(h2c[3][2], h2c[3][3]);

        // ---- layer 3: partial Z over own kt pair ----
        f32x4 zp = __builtin_amdgcn_mfma_f32_16x16x32_bf16(
            w3f[0], __builtin_bit_cast(bf16x8, q0), zinit, 0, 0, 0);
        zp = __builtin_amdgcn_mfma_f32_16x16x32_bf16(
            w3f[1], __builtin_bit_cast(bf16x8, q1), zp, 0, 0, 0);

        *ex2w = zp;
        __syncthreads();
        f32x4 z0 = ex2[0][lane];   // static slots; sum is commutative ->
        f32x4 z1 = ex2[1][lane];   // bit-identical in both waves

        // ---- V partial + X update (identical in both waves) ----
#pragma unroll
        for (int r = 0; r < 4; ++r) {
            float z  = z0[r] + z1[r];
            float wn = sqdt * e0[r];
            vacc = fmaf(z, wn, fmaf(0.01f * z, z, vacc));   // z*wn + dt/2*z^2
            x[r] = fmaf(x[r], 0.98f, wn);                   // (1-dt)*x + wn
        }

        e0 = e1; e1 = e2;
        t += dt;
    }

    // ---- final V reduction across the 4 q-groups (within this wave) ----
    float part = vacc;
    part += __shfl_xor(part, 16);
    part += __shfl_xor(part, 32);
    float v = V0[gr] + part;

    if (wv == 0) {
        *(f32x4*)&out[gr * D_ + q * 4] = x;
        if (q == 0) out[N_ * D_ + gr] = v;
    }
}

extern "C" void kernel_launch(void* const* d_in, const int* in_sizes, int n_in,
                              void* d_out, int out_size, void* d_ws, size_t ws_size,
                              hipStream_t stream)
{
    const float* X0 = (const float*)d_in[0];
    const float* V0 = (const float*)d_in[1];
    const float* Y  = (const float*)d_in[2];
    const float* nz = (const float*)d_in[3];
    const float* W1 = (const float*)d_in[4];
    const float* b1 = (const float*)d_in[5];
    const float* W2 = (const float*)d_in[6];
    const float* b2 = (const float*)d_in[7];
    const float* W3 = (const float*)d_in[8];
    const float* b3 = (const float*)d_in[9];
    float* out = (float*)d_out;

    sde_fused<<<N_ / 16, 128, 0, stream>>>(X0, V0, Y, nz, W1, b1, W2, b2, W3, b3, out);
}

// Round 6
// 139.087 us; speedup vs baseline: 3.7662x; 1.0522x over previous
//
#include <hip/hip_runtime.h>

typedef __bf16   bf16x8 __attribute__((ext_vector_type(8)));
typedef float    f32x4  __attribute__((ext_vector_type(4)));
typedef float    f32x2  __attribute__((ext_vector_type(2)));
typedef uint32_t u32x4  __attribute__((ext_vector_type(4)));

constexpr int N_ = 16384;
constexpr int D_ = 16;
constexpr int P_ = 8;
constexpr int H_ = 128;
constexpr int M_ = 50;

// pack two f32 -> one bf16x2 register word (round-half-up; 3 VALU ops)
__device__ __forceinline__ uint32_t pk_bf16(float a, float b) {
    uint32_t ua = __builtin_bit_cast(uint32_t, a) + 0x8000u;
    uint32_t ub = __builtin_bit_cast(uint32_t, b) + 0x8000u;
    return __builtin_amdgcn_perm(ub, ua, 0x07060302u);   // [a.hi16 | b.hi16]
}
__device__ __forceinline__ uint32_t pk_relu_bf16(float a, float b) {
    return pk_bf16(fmaxf(a, 0.0f), fmaxf(b, 0.0f));
}

// R6: single wave per 16-particle tile, full-H register-resident weights,
// zero LDS (R3 structure) + the key algorithmic unlock: X_{m+1} depends only
// on X_m and noise (Z never feeds back), so the 50 MLP evaluations are
// INDEPENDENT once X is rolled forward (4 fma/step). We process 2 steps per
// iteration as two independent dataflow chains in one basic block -> the
// scheduler interleaves their MFMAs/packs, hiding MFMA latency and VALU under
// the 88-MFMA-per-pair issue floor (~1707 cyc/pair).
__global__ __launch_bounds__(64, 1)
void sde_fused(const float* __restrict__ X0,
               const float* __restrict__ V0,
               const float* __restrict__ Yobs,
               const float* __restrict__ noise,
               const float* __restrict__ W1, const float* __restrict__ b1,
               const float* __restrict__ W2, const float* __restrict__ b2,
               const float* __restrict__ W3, const float* __restrict__ b3,
               float* __restrict__ out)
{
    const int lane = threadIdx.x;
    const int n    = lane & 15;
    const int q    = lane >> 4;
    const int gr   = blockIdx.x * 16 + n;

    const float dt   = 0.02f;
    const float sqdt = 0.1414213562373095f;

    // ---- weight fragments, A-operand layout A[m=lane&15][k=q*8+j] (as R3) ----
    bf16x8 w1f[8];
#pragma unroll
    for (int ct = 0; ct < 8; ++ct) {
        u32x4 u;
        u[0] = pk_bf16(W1[(1 + q * 4 + 0) * H_ + ct * 16 + n],
                       W1[(1 + q * 4 + 1) * H_ + ct * 16 + n]);
        u[1] = pk_bf16(W1[(1 + q * 4 + 2) * H_ + ct * 16 + n],
                       W1[(1 + q * 4 + 3) * H_ + ct * 16 + n]);
        u[2] = pk_bf16(W1[(17 + q * 2 + 0) * H_ + ct * 16 + n],
                       W1[(17 + q * 2 + 1) * H_ + ct * 16 + n]);
        u[3] = (q == 0) ? pk_bf16(b1[ct * 16 + n], W1[ct * 16 + n]) : 0u;
        w1f[ct] = __builtin_bit_cast(bf16x8, u);
    }
    bf16x8 w2f[8][4];
#pragma unroll
    for (int ct = 0; ct < 8; ++ct)
#pragma unroll
        for (int kt = 0; kt < 4; ++kt) {
            u32x4 u;
#pragma unroll
            for (int w = 0; w < 4; ++w) {
                int h0 = (kt * 2 + (w >> 1)) * 16 + q * 4 + (w & 1) * 2;
                u[w] = pk_bf16(W2[h0 * H_ + ct * 16 + n],
                               W2[(h0 + 1) * H_ + ct * 16 + n]);
            }
            w2f[ct][kt] = __builtin_bit_cast(bf16x8, u);
        }
    bf16x8 w3f[4];
#pragma unroll
    for (int kt = 0; kt < 4; ++kt) {
        u32x4 u;
#pragma unroll
        for (int w = 0; w < 4; ++w) {
            int h0 = (kt * 2 + (w >> 1)) * 16 + q * 4 + (w & 1) * 2;
            u[w] = pk_bf16(W3[h0 * D_ + n], W3[(h0 + 1) * D_ + n]);
        }
        w3f[kt] = __builtin_bit_cast(bf16x8, u);
    }
    f32x4 b2r[8];
#pragma unroll
    for (int ct = 0; ct < 8; ++ct)
#pragma unroll
        for (int r = 0; r < 4; ++r) b2r[ct][r] = b2[ct * 16 + q * 4 + r];
    f32x4 b3r;
#pragma unroll
    for (int r = 0; r < 4; ++r) b3r[r] = b3[q * 4 + r];

    // ---- state ----
    f32x4 x = *(const f32x4*)&X0[gr * D_ + q * 4];
    f32x2 y2 = *(const f32x2*)&Yobs[gr * P_ + q * 2];
    const uint32_t yw = pk_bf16(y2[0], y2[1]);

    const float* npb = noise + (size_t)gr * D_ + q * 4;
    const size_t stp = (size_t)N_ * D_;
    f32x4 e0 = *(const f32x4*)(npb + 0 * stp);
    f32x4 e1 = *(const f32x4*)(npb + 1 * stp);
    f32x4 e2 = *(const f32x4*)(npb + 2 * stp);
    f32x4 e3 = *(const f32x4*)(npb + 3 * stp);
    float tA = 0.0f, tB = dt;
    float vacc = 0.0f;

    // one full MLP evaluation (inlined twice per iteration; all indices static)
    auto mlp = [&](bf16x8 a0) -> f32x4 {
        f32x4 h1c[8];
#pragma unroll
        for (int ct = 0; ct < 8; ++ct)
            h1c[ct] = __builtin_amdgcn_mfma_f32_16x16x32_bf16(
                w1f[ct], a0, (f32x4){0.f, 0.f, 0.f, 0.f}, 0, 0, 0);
        bf16x8 h1b[4];
#pragma unroll
        for (int kt = 0; kt < 4; ++kt) {
            u32x4 u;
            u[0] = pk_relu_bf16(h1c[2 * kt][0], h1c[2 * kt][1]);
            u[1] = pk_relu_bf16(h1c[2 * kt][2], h1c[2 * kt][3]);
            u[2] = pk_relu_bf16(h1c[2 * kt + 1][0], h1c[2 * kt + 1][1]);
            u[3] = pk_relu_bf16(h1c[2 * kt + 1][2], h1c[2 * kt + 1][3]);
            h1b[kt] = __builtin_bit_cast(bf16x8, u);
        }
        f32x4 h2c[8];
#pragma unroll
        for (int ct = 0; ct < 8; ++ct) {
            f32x4 cc = b2r[ct];
#pragma unroll
            for (int kt = 0; kt < 4; ++kt)
                cc = __builtin_amdgcn_mfma_f32_16x16x32_bf16(w2f[ct][kt], h1b[kt], cc, 0, 0, 0);
            h2c[ct] = cc;
        }
        bf16x8 h2b[4];
#pragma unroll
        for (int kt = 0; kt < 4; ++kt) {
            u32x4 u;
            u[0] = pk_relu_bf16(h2c[2 * kt][0], h2c[2 * kt][1]);
            u[1] = pk_relu_bf16(h2c[2 * kt][2], h2c[2 * kt][3]);
            u[2] = pk_relu_bf16(h2c[2 * kt + 1][0], h2c[2 * kt + 1][1]);
            u[3] = pk_relu_bf16(h2c[2 * kt + 1][2], h2c[2 * kt + 1][3]);
            h2b[kt] = __builtin_bit_cast(bf16x8, u);
        }
        f32x4 za = __builtin_amdgcn_mfma_f32_16x16x32_bf16(w3f[0], h2b[0], b3r, 0, 0, 0);
        za = __builtin_amdgcn_mfma_f32_16x16x32_bf16(w3f[1], h2b[1], za, 0, 0, 0);
        f32x4 zb = __builtin_amdgcn_mfma_f32_16x16x32_bf16(
            w3f[2], h2b[2], (f32x4){0.f, 0.f, 0.f, 0.f}, 0, 0, 0);
        zb = __builtin_amdgcn_mfma_f32_16x16x32_bf16(w3f[3], h2b[3], zb, 0, 0, 0);
        f32x4 zr;
#pragma unroll
        for (int r = 0; r < 4; ++r) zr[r] = za[r] + zb[r];
        return zr;
    };

    for (int mm = 0; mm < M_ / 2; ++mm) {
        // prefetch the pair after next (clamped tail; duplicate loads are L1 hits)
        int sa = 2 * mm + 4; if (sa > M_ - 1) sa = M_ - 1;
        int sb = 2 * mm + 5; if (sb > M_ - 1) sb = M_ - 1;
        f32x4 e4 = *(const f32x4*)(npb + (size_t)sa * stp);
        f32x4 e5 = *(const f32x4*)(npb + (size_t)sb * stp);

        // ---- roll X forward for both steps (cheap, only sequential part) ----
        u32x4 auA;
        auA[0] = pk_bf16(x[0], x[1]);
        auA[1] = pk_bf16(x[2], x[3]);
        auA[2] = yw;
        auA[3] = (q == 0) ? pk_bf16(1.0f, tA) : 0u;
        f32x4 wnA, xB, wnB;
#pragma unroll
        for (int r = 0; r < 4; ++r) {
            wnA[r] = sqdt * e0[r];
            xB[r]  = fmaf(x[r], 0.98f, wnA[r]);
        }
        u32x4 auB;
        auB[0] = pk_bf16(xB[0], xB[1]);
        auB[1] = pk_bf16(xB[2], xB[3]);
        auB[2] = yw;
        auB[3] = (q == 0) ? pk_bf16(1.0f, tB) : 0u;
#pragma unroll
        for (int r = 0; r < 4; ++r) {
            wnB[r] = sqdt * e1[r];
            x[r]   = fmaf(xB[r], 0.98f, wnB[r]);
        }

        // ---- two independent MLP evaluations (scheduler interleaves) ----
        f32x4 zA = mlp(__builtin_bit_cast(bf16x8, auA));
        f32x4 zB = mlp(__builtin_bit_cast(bf16x8, auB));

        // ---- V accumulation ----
#pragma unroll
        for (int r = 0; r < 4; ++r)
            vacc = fmaf(zA[r], wnA[r], fmaf(0.01f * zA[r], zA[r], vacc));
#pragma unroll
        for (int r = 0; r < 4; ++r)
            vacc = fmaf(zB[r], wnB[r], fmaf(0.01f * zB[r], zB[r], vacc));

        e0 = e2; e1 = e3; e2 = e4; e3 = e5;
        tA += 0.04f; tB += 0.04f;
    }

    // ---- final V reduction across the 4 q-groups ----
    float part = vacc;
    part += __shfl_xor(part, 16);
    part += __shfl_xor(part, 32);
    float v = V0[gr] + part;

    *(f32x4*)&out[gr * D_ + q * 4] = x;
    if (q == 0) out[N_ * D_ + gr] = v;
}

extern "C" void kernel_launch(void* const* d_in, const int* in_sizes, int n_in,
                              void* d_out, int out_size, void* d_ws, size_t ws_size,
                              hipStream_t stream)
{
    const float* X0 = (const float*)d_in[0];
    const float* V0 = (const float*)d_in[1];
    const float* Y  = (const float*)d_in[2];
    const float* nz = (const float*)d_in[3];
    const float* W1 = (const float*)d_in[4];
    const float* b1 = (const float*)d_in[5];
    const float* W2 = (const float*)d_in[6];
    const float* b2 = (const float*)d_in[7];
    const float* W3 = (const float*)d_in[8];
    const float* b3 = (const float*)d_in[9];
    float* out = (float*)d_out;

    sde_fused<<<N_ / 16, 64, 0, stream>>>(X0, V0, Y, nz, W1, b1, W2, b2, W3, b3, out);
}